// Round 8
// baseline (221.779 us; speedup 1.0000x reference)
//
#include <hip/hip_runtime.h>
#include <hip/hip_bf16.h>
#include <math.h>

#define N_NODES 50000
#define E_RAW   800000
#define E_TOT   850000
#define NEG_SLOPE 0.2f
#define CAP 64    // ELL slots per node; deg = Poisson(16)+1, P(>64) ~ 1e-13

// two-level binning parameters
#define NBKT   392     // buckets of 128 dst nodes: b = d >> 7 (49999>>7 = 390)
#define BCAP   2944    // slots per bucket; mean 2176, sd ~47 -> mean+16sd
#define SCHUNK 4096    // edges per binning block
#define SB     208     // ceil(E_TOT / SCHUNK)

typedef __attribute__((ext_vector_type(8))) short short8;
typedef __attribute__((ext_vector_type(4))) float f32x4;
typedef __attribute__((ext_vector_type(4))) unsigned short ushort4_t;

__device__ __forceinline__ short f2bf(float f) {
    __hip_bfloat16 h = __float2bfloat16(f);
    return *reinterpret_cast<short*>(&h);
}
__device__ __forceinline__ unsigned int f2bfu(float f) {
    __hip_bfloat16 h = __float2bfloat16(f);
    return (unsigned int)*reinterpret_cast<unsigned short*>(&h);
}
__device__ __forceinline__ float bflo(unsigned int u) {
    return __uint_as_float(u << 16);
}
__device__ __forceinline__ float bfhi(unsigned int u) {
    return __uint_as_float(u & 0xffff0000u);
}
__device__ __forceinline__ float bf2f(short v) {
    return __uint_as_float(((unsigned int)(unsigned short)v) << 16);
}
__device__ __forceinline__ void fma8(float al, const uint4& h, float* acc) {
    acc[0] = fmaf(al, bflo(h.x), acc[0]);
    acc[1] = fmaf(al, bfhi(h.x), acc[1]);
    acc[2] = fmaf(al, bflo(h.y), acc[2]);
    acc[3] = fmaf(al, bfhi(h.y), acc[3]);
    acc[4] = fmaf(al, bflo(h.z), acc[4]);
    acc[5] = fmaf(al, bfhi(h.z), acc[5]);
    acc[6] = fmaf(al, bflo(h.w), acc[6]);
    acc[7] = fmaf(al, bfhi(h.w), acc[7]);
}
__device__ __forceinline__ void fma4(float al, const uint2& h, float* acc) {
    acc[0] = fmaf(al, bflo(h.x), acc[0]);
    acc[1] = fmaf(al, bfhi(h.x), acc[1]);
    acc[2] = fmaf(al, bflo(h.y), acc[2]);
    acc[3] = fmaf(al, bfhi(h.y), acc[3]);
}

// ============ W -> B-fragment-order bf16 swizzle + gcnt zero + w~ vectors ====
template<int K, int N>
__device__ __forceinline__ void wf_body(
        int idx, const float* __restrict__ W, short* __restrict__ Wf) {
    constexpr int NT = N / 16;
    const int j  = idx & 7;
    const int n  = (idx >> 3) & 15;
    const int q  = (idx >> 7) & 3;
    const int t  = (idx >> 9) % NT;
    const int kc = idx / (512 * NT);
    const int k   = kc * 32 + q * 8 + j;
    const int col = t * 16 + n;
    Wf[idx] = f2bf(W[(size_t)k * N + col]);
}

__global__ __launch_bounds__(256) void gat_wf12_kernel(
        const float* __restrict__ W1, short* __restrict__ Wf1,
        const float* __restrict__ W2, short* __restrict__ Wf2,
        const float* __restrict__ att_src2, const float* __restrict__ att_dst2,
        float* __restrict__ wtS, float* __restrict__ wtD,
        int* __restrict__ gcnt) {
    if (blockIdx.x == 0) {
        gcnt[threadIdx.x] = 0;
        gcnt[threadIdx.x + 256] = 0;
        // w~ = W2 @ att vectors: layer-2 scores without materializing h2
        if (threadIdx.x < 128) {
            float s = 0.0f, d = 0.0f;
            for (int n = 0; n < 64; ++n) {
                const float w = W2[threadIdx.x * 64 + n];
                s = fmaf(w, att_src2[n], s);
                d = fmaf(w, att_dst2[n], d);
            }
            wtS[threadIdx.x] = s;
            wtD[threadIdx.x] = d;
        }
    }
    int idx = blockIdx.x * 256 + threadIdx.x;
    if (idx < 256 * 128) {
        wf_body<256, 128>(idx, W1, Wf1);
    } else {
        idx -= 256 * 128;
        if (idx < 128 * 64) wf_body<128, 64>(idx, W2, Wf2);
    }
}

// ============ MFMA GEMM + fused attention scores (layer 1) ============
// 4 waves/block; wave owns 16 rows x N cols. A from global (4-deep register
// ring prefetch across kc), B from swizzled Wf.
template<int K, int N>
__device__ __forceinline__ void gemm_att_body(
        const int blk,
        const float* __restrict__ xf, const short* __restrict__ Wf,
        const float* __restrict__ att_src, const float* __restrict__ att_dst,
        short* __restrict__ h_bf,
        float* __restrict__ a_src, float* __restrict__ a_dst) {
    constexpr int NT = N / 16;
    constexpr int KC = K / 32;
    constexpr int PF = KC < 4 ? KC : 4;      // prefetch depth
    const int tid  = threadIdx.x;
    const int lane = tid & 63;
    const int wv   = tid >> 6;
    const int mrow = lane & 15;
    const int q    = lane >> 4;

    const int row0 = blk * 64 + wv * 16;
    const int rowA = row0 + mrow;
    const int rowAc = rowA < N_NODES ? rowA : 0;
    const float* xrow = &xf[(size_t)rowAc * K + q * 8];

    f32x4 acc[NT];
    #pragma unroll
    for (int t = 0; t < NT; ++t) acc[t] = f32x4{0.f, 0.f, 0.f, 0.f};

    float4 xa[PF], xb[PF];                   // ring buffer, slot kc % PF
    #pragma unroll
    for (int kc = 0; kc < PF; ++kc) {
        xa[kc] = *(const float4*)&xrow[kc * 32];
        xb[kc] = *(const float4*)&xrow[kc * 32 + 4];
    }

    #pragma unroll
    for (int kc = 0; kc < KC; ++kc) {
        const int sl = kc % PF;
        short8 a;
        a[0] = f2bf(xa[sl].x); a[1] = f2bf(xa[sl].y);
        a[2] = f2bf(xa[sl].z); a[3] = f2bf(xa[sl].w);
        a[4] = f2bf(xb[sl].x); a[5] = f2bf(xb[sl].y);
        a[6] = f2bf(xb[sl].z); a[7] = f2bf(xb[sl].w);
        if (kc + PF < KC) {                  // refill slot with kc+PF
            xa[sl] = *(const float4*)&xrow[(kc + PF) * 32];
            xb[sl] = *(const float4*)&xrow[(kc + PF) * 32 + 4];
        }
        #pragma unroll
        for (int t = 0; t < NT; ++t) {
            const short8 b = *(const short8*)&Wf[((size_t)(kc * NT + t) * 64 + lane) * 8];
            acc[t] = __builtin_amdgcn_mfma_f32_16x16x32_bf16(a, b, acc[t], 0, 0, 0);
        }
    }

    // D layout: col = mrow, row = q*4 + r
    #pragma unroll
    for (int r = 0; r < 4; ++r) {
        const int rowD = row0 + q * 4 + r;
        float ps = 0.0f, pd = 0.0f;
        #pragma unroll
        for (int t = 0; t < NT; ++t) {
            const int col = t * 16 + mrow;
            ps = fmaf(acc[t][r], att_src[col], ps);
            pd = fmaf(acc[t][r], att_dst[col], pd);
        }
        #pragma unroll
        for (int off = 8; off > 0; off >>= 1) {
            ps += __shfl_xor(ps, off);
            pd += __shfl_xor(pd, off);
        }
        if (rowD < N_NODES) {
            if (mrow == 0) { a_src[rowD] = ps; a_dst[rowD] = pd; }
            #pragma unroll
            for (int t = 0; t < NT; ++t)
                h_bf[(size_t)rowD * N + t * 16 + mrow] = f2bf(acc[t][r]);
        }
    }
}

// ===== fat kernel: layer-1 GEMM (blocks [0,GB)) + coarse edge binning [GB,..) =====
template<int K, int N>
__global__ __launch_bounds__(256) void gat_fat1_kernel(
        const float* __restrict__ xf, const short* __restrict__ Wf,
        const float* __restrict__ att_src, const float* __restrict__ att_dst,
        short* __restrict__ h_bf,
        float* __restrict__ a_src, float* __restrict__ a_dst,
        const int* __restrict__ ei, int* __restrict__ gcnt,
        unsigned int* __restrict__ buf, int GB) {
    __shared__ int hist[NBKT];
    __shared__ int base[NBKT];
    if ((int)blockIdx.x < GB) {
        gemm_att_body<K, N>(blockIdx.x, xf, Wf,
                            att_src, att_dst, h_bf, a_src, a_dst);
    } else {
        const int sb = (int)blockIdx.x - GB;
        const int c0 = sb * SCHUNK;
        const int c1 = (c0 + SCHUNK < E_TOT) ? c0 + SCHUNK : E_TOT;
        for (int t = threadIdx.x; t < NBKT; t += 256) hist[t] = 0;
        __syncthreads();
        // pass 1: histogram by coarse bucket
        for (int i = c0 + threadIdx.x; i < c1; i += 256) {
            const int d = (i < E_RAW) ? ei[E_RAW + i] : (i - E_RAW);
            atomicAdd(&hist[d >> 7], 1);
        }
        __syncthreads();
        // reserve this block's contiguous run in each bucket
        for (int t = threadIdx.x; t < NBKT; t += 256)
            base[t] = atomicAdd(&gcnt[t], hist[t]);
        __syncthreads();
        for (int t = threadIdx.x; t < NBKT; t += 256) hist[t] = 0;
        __syncthreads();
        // pass 2: grouped scatter of packed (s<<7 | d&127) entries
        for (int i = c0 + threadIdx.x; i < c1; i += 256) {
            int s, d;
            if (i < E_RAW) { s = ei[i]; d = ei[E_RAW + i]; }
            else           { s = d = i - E_RAW; }
            const int b = d >> 7;
            const int p = base[b] + atomicAdd(&hist[b], 1);
            if (p < BCAP)
                buf[(size_t)b * BCAP + p] =
                    ((unsigned int)s << 7) | (unsigned int)(d & 127);
        }
    }
}

// ===== bucket -> ELL expansion: one block per bucket, LDS slot tickets =====
__global__ __launch_bounds__(256) void gat_ell_kernel(
        const unsigned int* __restrict__ buf, const int* __restrict__ gcnt,
        int* __restrict__ cnt, unsigned short* __restrict__ srcs) {
    const int b = blockIdx.x;
    __shared__ unsigned int c2[128];
    if (threadIdx.x < 128) c2[threadIdx.x] = 0;
    __syncthreads();
    int n = gcnt[b];
    n = n < BCAP ? n : BCAP;
    const unsigned int* bb = buf + (size_t)b * BCAP;
    for (int i = threadIdx.x; i < n; i += 256) {
        const unsigned int e = bb[i];
        const int dl = (int)(e & 127u);
        const unsigned int s = e >> 7;
        const unsigned int c = atomicAdd(&c2[dl], 1u);
        if (c < CAP)
            srcs[((size_t)((b << 7) + dl) << 6) + c] = (unsigned short)s;
    }
    __syncthreads();
    const int d = (b << 7) + threadIdx.x;
    if (threadIdx.x < 128 && d < N_NODES) {
        unsigned int c = c2[threadIdx.x];
        cnt[d] = (int)(c < CAP ? c : CAP);
    }
}

// ===== shared stage 1+2: per-dst softmax alphas into LDS =====
// Block covers 16 dsts; thread t -> dst t>>4, slots (t&15)*4..+3. Slots >= deg
// are SANITIZED to src=0 with alpha=0, so gather loops need no tail predication
// (0 * finite(row 0) == 0).
__device__ __forceinline__ void softmax_stage(
        const int* __restrict__ cnt, const unsigned short* __restrict__ srcs,
        const float* __restrict__ a_src, const float* __restrict__ a_dst,
        const int d0, float* lalpha, unsigned short* lsrc,
        int* ldeg, float* ladst) {
    const int tid = threadIdx.x;
    if (tid < 16) {
        const int d = d0 + tid;
        int dg = cnt[d];
        ldeg[tid]  = dg < CAP ? dg : CAP;
        ladst[tid] = a_dst[d];
    }
    __syncthreads();
    const int dl = tid >> 4;
    const int so = (tid & 15) * 4;
    const int dg = ldeg[dl];
    const float ad = ladst[dl];
    const ushort4_t s4 =
        *(const ushort4_t*)(srcs + ((size_t)(d0 + dl) << 6) + so);
    float e[4];
    ushort4_t s4w;
    #pragma unroll
    for (int i = 0; i < 4; ++i) {
        if (so + i < dg) {
            const float t = a_src[(int)s4[i]] + ad;
            e[i] = t > 0.0f ? t : NEG_SLOPE * t;
            s4w[i] = s4[i];
        } else {
            e[i] = -1e30f;
            s4w[i] = 0;                      // safe row; alpha will be 0
        }
    }
    float m = fmaxf(fmaxf(e[0], e[1]), fmaxf(e[2], e[3]));
    #pragma unroll
    for (int off = 1; off < 16; off <<= 1) m = fmaxf(m, __shfl_xor(m, off));
    float ex[4], ss = 0.0f;
    #pragma unroll
    for (int i = 0; i < 4; ++i) { ex[i] = __expf(e[i] - m); ss += ex[i]; }
    #pragma unroll
    for (int off = 1; off < 16; off <<= 1) ss += __shfl_xor(ss, off);
    const float rinv = 1.0f / ss;            // ss >= 1 (self-loop => deg >= 1)
    float4 av;
    av.x = ex[0] * rinv; av.y = ex[1] * rinv;
    av.z = ex[2] * rinv; av.w = ex[3] * rinv;
    *(float4*)&lalpha[(dl << 6) + so] = av;
    *(ushort4_t*)&lsrc[(dl << 6) + so] = s4w;
}

// ===== layer-1 aggregation, XCD-pinned column slices =====
// blockIdx = group*4 + slice. Consecutive blockIdx round-robin across the 8
// XCDs, so slice s runs only on XCDs {s, s+4}: its 32-col (64 B/row) slice of
// hbf1 (3.2 MB) stays L2-resident per XCD instead of being replicated 8x.
// Lane layout: gq = dst (4/wave), e = edge slot (4), c4 = col quarter (8 cols).
__global__ __launch_bounds__(256, 8) void gat_aggr1s_kernel(
        const int* __restrict__ cnt, const unsigned short* __restrict__ srcs,
        const float* __restrict__ a_src, const float* __restrict__ a_dst,
        const unsigned short* __restrict__ h_bf, const float* __restrict__ bias,
        short* __restrict__ agg1) {
    __shared__ __align__(16) float lalpha[1024];   // 16 dsts x 64 slots
    __shared__ __align__(16) unsigned short lsrc[1024];
    __shared__ int   ldeg[16];
    __shared__ float ladst[16];
    const int tid   = threadIdx.x;
    const int slice = blockIdx.x & 3;
    const int d0    = (blockIdx.x >> 2) * 16;      // 3125 groups x 16 = 50000

    softmax_stage(cnt, srcs, a_src, a_dst, d0, lalpha, lsrc, ldeg, ladst);
    __syncthreads();

    const int lane = tid & 63;
    const int wv   = tid >> 6;
    const int gq   = lane >> 4;
    const int e    = (lane >> 2) & 3;
    const int c4   = lane & 3;
    const int dl   = wv * 4 + gq;
    const int deg  = ldeg[dl];
    const int base = dl << 6;
    const int col0 = slice * 32 + c4 * 8;    // bf16 column offset

    float acc[8];
    #pragma unroll
    for (int c = 0; c < 8; ++c) acc[c] = 0.0f;

    const int deg4 = (deg + 3) & ~3;         // sanitized slots: no tail guards
    int j = 0;
    for (; j + 8 <= deg4; j += 8) {          // 2 gathers in flight per lane
        const int s0    = (int)lsrc[base + j + e];
        const int s1    = (int)lsrc[base + j + 4 + e];
        const float al0 = lalpha[base + j + e];
        const float al1 = lalpha[base + j + 4 + e];
        const uint4 h0 = *(const uint4*)(h_bf + (size_t)s0 * 128 + col0);
        const uint4 h1 = *(const uint4*)(h_bf + (size_t)s1 * 128 + col0);
        fma8(al0, h0, acc);
        fma8(al1, h1, acc);
    }
    if (j < deg4) {
        const int s0    = (int)lsrc[base + j + e];
        const float al0 = lalpha[base + j + e];
        const uint4 h0 = *(const uint4*)(h_bf + (size_t)s0 * 128 + col0);
        fma8(al0, h0, acc);
    }

    // reduce over edge slots (lane bits 2,3)
    #pragma unroll
    for (int c = 0; c < 8; ++c) {
        acc[c] += __shfl_xor(acc[c], 4);
        acc[c] += __shfl_xor(acc[c], 8);
    }

    // e == 0 lanes: bias + relu -> bf16 -> agg1 cols [col0, col0+8)
    if (e == 0) {
        const float4 b0 = *(const float4*)&bias[col0];
        const float4 b1 = *(const float4*)&bias[col0 + 4];
        float v[8];
        v[0] = fmaxf(acc[0] + b0.x, 0.0f); v[1] = fmaxf(acc[1] + b0.y, 0.0f);
        v[2] = fmaxf(acc[2] + b0.z, 0.0f); v[3] = fmaxf(acc[3] + b0.w, 0.0f);
        v[4] = fmaxf(acc[4] + b1.x, 0.0f); v[5] = fmaxf(acc[5] + b1.y, 0.0f);
        v[6] = fmaxf(acc[6] + b1.z, 0.0f); v[7] = fmaxf(acc[7] + b1.w, 0.0f);
        uint4 p;
        p.x = f2bfu(v[0]) | (f2bfu(v[1]) << 16);
        p.y = f2bfu(v[2]) | (f2bfu(v[3]) << 16);
        p.z = f2bfu(v[4]) | (f2bfu(v[5]) << 16);
        p.w = f2bfu(v[6]) | (f2bfu(v[7]) << 16);
        *(uint4*)&agg1[(size_t)(d0 + dl) * 128 + col0] = p;
    }
}

// ===== layer-2 GEMM + att scores (w~ trick) =====
// h2 = agg1 @ W2 via MFMA; a_src2/a_dst2 = agg1 . w~ computed from the A
// fragments directly (no score dependence on the D layout).
__global__ __launch_bounds__(256) void gat_gemm2_kernel(
        const short* __restrict__ agg1, const short* __restrict__ Wf2,
        const float* __restrict__ wtS, const float* __restrict__ wtD,
        short* __restrict__ hbf2,
        float* __restrict__ a_src2, float* __restrict__ a_dst2) {
    const int tid  = threadIdx.x;
    const int lane = tid & 63;
    const int wv   = tid >> 6;
    const int mrow = lane & 15;
    const int q    = lane >> 4;
    const int row0 = blockIdx.x * 64 + wv * 16;
    const int rowA = row0 + mrow;
    const int rowAc = rowA < N_NODES ? rowA : 0;

    f32x4 acc[4];
    #pragma unroll
    for (int t = 0; t < 4; ++t) acc[t] = f32x4{0.f, 0.f, 0.f, 0.f};
    float ps = 0.0f, pd = 0.0f;

    #pragma unroll
    for (int kc = 0; kc < 4; ++kc) {
        const short8 a = *(const short8*)&agg1[(size_t)rowAc * 128 + kc * 32 + q * 8];
        #pragma unroll
        for (int jj = 0; jj < 8; ++jj) {
            const float av = bf2f(a[jj]);
            ps = fmaf(av, wtS[kc * 32 + q * 8 + jj], ps);
            pd = fmaf(av, wtD[kc * 32 + q * 8 + jj], pd);
        }
        #pragma unroll
        for (int t = 0; t < 4; ++t) {
            const short8 b = *(const short8*)&Wf2[((size_t)(kc * 4 + t) * 64 + lane) * 8];
            acc[t] = __builtin_amdgcn_mfma_f32_16x16x32_bf16(a, b, acc[t], 0, 0, 0);
        }
    }

    // scores: reduce partial dots over q (lane bits 4,5); row = mrow
    ps += __shfl_xor(ps, 16); ps += __shfl_xor(ps, 32);
    pd += __shfl_xor(pd, 16); pd += __shfl_xor(pd, 32);
    if (lane < 16 && rowA < N_NODES) {
        a_src2[rowA] = ps;
        a_dst2[rowA] = pd;
    }

    // D layout: col = mrow, row = q*4 + r
    #pragma unroll
    for (int r = 0; r < 4; ++r) {
        const int rowD = row0 + q * 4 + r;
        if (rowD < N_NODES) {
            #pragma unroll
            for (int t = 0; t < 4; ++t)
                hbf2[(size_t)rowD * 64 + t * 16 + mrow] = f2bf(acc[t][r]);
        }
    }
}

// ===== layer-2 aggregation + bias + log_softmax (N=64) =====
__global__ __launch_bounds__(256, 8) void gat_aggr2_kernel(
        const int* __restrict__ cnt, const unsigned short* __restrict__ srcs,
        const float* __restrict__ a_src, const float* __restrict__ a_dst,
        const unsigned short* __restrict__ h_bf, const float* __restrict__ bias,
        float* __restrict__ outf) {
    constexpr int N = 64;
    __shared__ __align__(16) float lalpha[1024];   // 16 dsts x 64 slots
    __shared__ __align__(16) unsigned short lsrc[1024];
    __shared__ int   ldeg[16];
    __shared__ float ladst[16];
    const int tid = threadIdx.x;
    const int d0 = blockIdx.x * 16;          // 3125 blocks x 16 = 50000 exact

    softmax_stage(cnt, srcs, a_src, a_dst, d0, lalpha, lsrc, ldeg, ladst);
    __syncthreads();

    // ---- stage 3: wave w -> dsts w*4..w*4+3; group g (16 lanes) owns one ----
    const int lane = tid & 63;
    const int g    = lane >> 4;
    const int sub  = lane & 15;
    const int dl   = (tid >> 6) * 4 + g;
    const int d    = d0 + dl;
    const int deg  = ldeg[dl];
    const int base = dl << 6;

    float acc[4];
    #pragma unroll
    for (int c = 0; c < 4; ++c) acc[c] = 0.0f;

    const int deg4 = (deg + 3) & ~3;         // sanitized slots: uniform loop
    for (int j = 0; j < deg4; j += 4) {      // 4 gathers in flight
        const ushort4_t s4 = *(const ushort4_t*)&lsrc[base + j];
        const float4    a4 = *(const float4*)&lalpha[base + j];
        const uint2 h0 = *(const uint2*)(h_bf + (size_t)s4[0] * N + sub * 4);
        const uint2 h1 = *(const uint2*)(h_bf + (size_t)s4[1] * N + sub * 4);
        const uint2 h2 = *(const uint2*)(h_bf + (size_t)s4[2] * N + sub * 4);
        const uint2 h3 = *(const uint2*)(h_bf + (size_t)s4[3] * N + sub * 4);
        fma4(a4.x, h0, acc); fma4(a4.y, h1, acc);
        fma4(a4.z, h2, acc); fma4(a4.w, h3, acc);
    }

    // ---- epilogue: bias + log_softmax; lane sub holds cols sub*4..+3 ----
    float v[4];
    #pragma unroll
    for (int c = 0; c < 4; ++c) v[c] = acc[c] + bias[sub * 4 + c];
    float mm = fmaxf(fmaxf(v[0], v[1]), fmaxf(v[2], v[3]));
    #pragma unroll
    for (int off = 1; off < 16; off <<= 1) mm = fmaxf(mm, __shfl_xor(mm, off));
    float es = __expf(v[0] - mm) + __expf(v[1] - mm)
             + __expf(v[2] - mm) + __expf(v[3] - mm);
    #pragma unroll
    for (int off = 1; off < 16; off <<= 1) es += __shfl_xor(es, off);
    const float ls = logf(es);
    float4 o;
    o.x = v[0] - mm - ls; o.y = v[1] - mm - ls;
    o.z = v[2] - mm - ls; o.w = v[3] - mm - ls;
    *(float4*)&outf[(size_t)d * N + sub * 4] = o;
}

extern "C" void kernel_launch(void* const* d_in, const int* in_sizes, int n_in,
                              void* d_out, int out_size, void* d_ws, size_t ws_size,
                              hipStream_t stream) {
    const float* x        = (const float*)d_in[0];
    const int*   ei       = (const int*)  d_in[1];
    const float* W1       = (const float*)d_in[2];
    const float* att_src1 = (const float*)d_in[3];
    const float* att_dst1 = (const float*)d_in[4];
    const float* b1       = (const float*)d_in[5];
    const float* W2       = (const float*)d_in[6];
    const float* att_src2 = (const float*)d_in[7];
    const float* att_dst2 = (const float*)d_in[8];
    const float* b2       = (const float*)d_in[9];
    float* out = (float*)d_out;
    float* ws  = (float*)d_ws;

    // workspace layout (float units; 16B alignment holds for bf16 buffers)
    float* a_src1 = ws;                              //  50,000
    float* a_dst1 = a_src1 + 50000;
    float* a_src2 = a_dst1 + 50000;
    float* a_dst2 = a_src2 + 50000;
    int*   cnt    = (int*)(a_dst2 + 50000);          //  50,000
    int*   gcnt   = cnt + 50000;                     //     512 (392 used)
    float* wtS    = (float*)(gcnt + 512);            //     128
    float* wtD    = wtS + 128;                       //     128
    unsigned int*   buf  = (unsigned int*)(wtD + 128);    // 392*2944 u32
    unsigned short* srcs = (unsigned short*)(buf + (size_t)NBKT * BCAP); // 3.2M u16
    short* hbf1   = (short*)(srcs + (size_t)N_NODES * CAP);  // 6,400,000 bf16
    short* agg1   = hbf1  + 6400000;                 // 6,400,000 bf16
    short* hbf2   = agg1  + 6400000;                 // 3,200,000 bf16
    short* Wf1    = hbf2  + 3200000;                 //    32,768 bf16
    short* Wf2    = Wf1   + 32768;                   //     8,192 bf16

    const int GB = (N_NODES + 63) / 64;              // 782 gemm blocks

    // ---- weight swizzles + gcnt zero + w~ (single launch) ----
    gat_wf12_kernel<<<160, 256, 0, stream>>>(
        W1, Wf1, W2, Wf2, att_src2, att_dst2, wtS, wtD, gcnt);

    // ---- layer-1 GEMM + coarse edge binning (independent, co-scheduled) ----
    gat_fat1_kernel<256, 128><<<GB + SB, 256, 0, stream>>>(
        x, Wf1, att_src1, att_dst1, hbf1, a_src1, a_dst1,
        ei, gcnt, buf, GB);

    // ---- bucket lists -> ELL (cnt + ushort srcs), XCD-local writes ----
    gat_ell_kernel<<<NBKT, 256, 0, stream>>>(buf, gcnt, cnt, srcs);

    // ---- layer-1 aggregation, 4 XCD-pinned column slices ----
    gat_aggr1s_kernel<<<3125 * 4, 256, 0, stream>>>(
        cnt, srcs, a_src1, a_dst1, (const unsigned short*)hbf1, b1, agg1);

    // ---- layer-2 GEMM + att scores (w~ trick) ----
    gat_gemm2_kernel<<<GB, 256, 0, stream>>>(
        agg1, Wf2, wtS, wtD, hbf2, a_src2, a_dst2);

    // ---- layer-2 aggregation + log_softmax ----
    gat_aggr2_kernel<<<3125, 256, 0, stream>>>(
        cnt, srcs, a_src2, a_dst2, (const unsigned short*)hbf2, b2,
        out);
}

// Round 9
// 198.239 us; speedup vs baseline: 1.1187x; 1.1187x over previous
//
#include <hip/hip_runtime.h>
#include <hip/hip_bf16.h>
#include <math.h>

#define N_NODES 50000
#define E_RAW   800000
#define E_TOT   850000
#define NEG_SLOPE 0.2f
#define CAP 64    // ELL slots per node; deg = Poisson(16)+1, P(>64) ~ 1e-13

// two-level binning parameters
#define NBKT   392     // buckets of 128 dst nodes: b = d >> 7 (49999>>7 = 390)
#define BCAP   2944    // slots per bucket; mean 2176, sd ~47 -> mean+16sd
#define SCHUNK 4096    // edges per binning block
#define SB     208     // ceil(E_TOT / SCHUNK)

typedef __attribute__((ext_vector_type(8))) short short8;
typedef __attribute__((ext_vector_type(4))) float f32x4;
typedef __attribute__((ext_vector_type(4))) unsigned short ushort4_t;

__device__ __forceinline__ short f2bf(float f) {
    __hip_bfloat16 h = __float2bfloat16(f);
    return *reinterpret_cast<short*>(&h);
}
__device__ __forceinline__ unsigned int f2bfu(float f) {
    __hip_bfloat16 h = __float2bfloat16(f);
    return (unsigned int)*reinterpret_cast<unsigned short*>(&h);
}
__device__ __forceinline__ float bflo(unsigned int u) {
    return __uint_as_float(u << 16);
}
__device__ __forceinline__ float bfhi(unsigned int u) {
    return __uint_as_float(u & 0xffff0000u);
}
__device__ __forceinline__ void fma8(float al, const uint4& h, float* acc) {
    acc[0] = fmaf(al, bflo(h.x), acc[0]);
    acc[1] = fmaf(al, bfhi(h.x), acc[1]);
    acc[2] = fmaf(al, bflo(h.y), acc[2]);
    acc[3] = fmaf(al, bfhi(h.y), acc[3]);
    acc[4] = fmaf(al, bflo(h.z), acc[4]);
    acc[5] = fmaf(al, bfhi(h.z), acc[5]);
    acc[6] = fmaf(al, bflo(h.w), acc[6]);
    acc[7] = fmaf(al, bfhi(h.w), acc[7]);
}
__device__ __forceinline__ void fma4(float al, const uint2& h, float* acc) {
    acc[0] = fmaf(al, bflo(h.x), acc[0]);
    acc[1] = fmaf(al, bfhi(h.x), acc[1]);
    acc[2] = fmaf(al, bflo(h.y), acc[2]);
    acc[3] = fmaf(al, bfhi(h.y), acc[3]);
}

// ============ W -> B-fragment-order bf16 swizzle (both weights, 1 launch) ====
// Also zeroes gcnt (replaces the hipMemsetAsync dispatch).
template<int K, int N>
__device__ __forceinline__ void wf_body(
        int idx, const float* __restrict__ W, short* __restrict__ Wf) {
    constexpr int NT = N / 16;
    const int j  = idx & 7;
    const int n  = (idx >> 3) & 15;
    const int q  = (idx >> 7) & 3;
    const int t  = (idx >> 9) % NT;
    const int kc = idx / (512 * NT);
    const int k   = kc * 32 + q * 8 + j;
    const int col = t * 16 + n;
    Wf[idx] = f2bf(W[(size_t)k * N + col]);
}

__global__ __launch_bounds__(256) void gat_wf12_kernel(
        const float* __restrict__ W1, short* __restrict__ Wf1,
        const float* __restrict__ W2, short* __restrict__ Wf2,
        int* __restrict__ gcnt) {
    if (blockIdx.x == 0) {
        gcnt[threadIdx.x] = 0;
        gcnt[threadIdx.x + 256] = 0;
    }
    int idx = blockIdx.x * 256 + threadIdx.x;
    if (idx < 256 * 128) {
        wf_body<256, 128>(idx, W1, Wf1);
    } else {
        idx -= 256 * 128;
        if (idx < 128 * 64) wf_body<128, 64>(idx, W2, Wf2);
    }
}

// ============ MFMA GEMM + fused attention scores (layer 1) ============
// 4 waves/block; wave owns 16 rows x N cols. A from global (4-deep register
// ring prefetch across kc), B from swizzled Wf.
template<int K, int N>
__device__ __forceinline__ void gemm_att_body(
        const int blk,
        const float* __restrict__ xf, const short* __restrict__ Wf,
        const float* __restrict__ att_src, const float* __restrict__ att_dst,
        short* __restrict__ h_bf,
        float* __restrict__ a_src, float* __restrict__ a_dst) {
    constexpr int NT = N / 16;
    constexpr int KC = K / 32;
    constexpr int PF = KC < 4 ? KC : 4;      // prefetch depth
    const int tid  = threadIdx.x;
    const int lane = tid & 63;
    const int wv   = tid >> 6;
    const int mrow = lane & 15;
    const int q    = lane >> 4;

    const int row0 = blk * 64 + wv * 16;
    const int rowA = row0 + mrow;
    const int rowAc = rowA < N_NODES ? rowA : 0;
    const float* xrow = &xf[(size_t)rowAc * K + q * 8];

    f32x4 acc[NT];
    #pragma unroll
    for (int t = 0; t < NT; ++t) acc[t] = f32x4{0.f, 0.f, 0.f, 0.f};

    float4 xa[PF], xb[PF];                   // ring buffer, slot kc % PF
    #pragma unroll
    for (int kc = 0; kc < PF; ++kc) {
        xa[kc] = *(const float4*)&xrow[kc * 32];
        xb[kc] = *(const float4*)&xrow[kc * 32 + 4];
    }

    #pragma unroll
    for (int kc = 0; kc < KC; ++kc) {
        const int sl = kc % PF;
        short8 a;
        a[0] = f2bf(xa[sl].x); a[1] = f2bf(xa[sl].y);
        a[2] = f2bf(xa[sl].z); a[3] = f2bf(xa[sl].w);
        a[4] = f2bf(xb[sl].x); a[5] = f2bf(xb[sl].y);
        a[6] = f2bf(xb[sl].z); a[7] = f2bf(xb[sl].w);
        if (kc + PF < KC) {                  // refill slot with kc+PF
            xa[sl] = *(const float4*)&xrow[(kc + PF) * 32];
            xb[sl] = *(const float4*)&xrow[(kc + PF) * 32 + 4];
        }
        #pragma unroll
        for (int t = 0; t < NT; ++t) {
            const short8 b = *(const short8*)&Wf[((size_t)(kc * NT + t) * 64 + lane) * 8];
            acc[t] = __builtin_amdgcn_mfma_f32_16x16x32_bf16(a, b, acc[t], 0, 0, 0);
        }
    }

    // D layout: col = mrow, row = q*4 + r
    #pragma unroll
    for (int r = 0; r < 4; ++r) {
        const int rowD = row0 + q * 4 + r;
        float ps = 0.0f, pd = 0.0f;
        #pragma unroll
        for (int t = 0; t < NT; ++t) {
            const int col = t * 16 + mrow;
            ps = fmaf(acc[t][r], att_src[col], ps);
            pd = fmaf(acc[t][r], att_dst[col], pd);
        }
        #pragma unroll
        for (int off = 8; off > 0; off >>= 1) {
            ps += __shfl_xor(ps, off);
            pd += __shfl_xor(pd, off);
        }
        if (rowD < N_NODES) {
            if (mrow == 0) { a_src[rowD] = ps; a_dst[rowD] = pd; }
            #pragma unroll
            for (int t = 0; t < NT; ++t)
                h_bf[(size_t)rowD * N + t * 16 + mrow] = f2bf(acc[t][r]);
        }
    }
}

// ===== fat kernel: layer-1 GEMM (blocks [0,GB)) + coarse edge binning [GB,..) =====
template<int K, int N>
__global__ __launch_bounds__(256) void gat_fat1_kernel(
        const float* __restrict__ xf, const short* __restrict__ Wf,
        const float* __restrict__ att_src, const float* __restrict__ att_dst,
        short* __restrict__ h_bf,
        float* __restrict__ a_src, float* __restrict__ a_dst,
        const int* __restrict__ ei, int* __restrict__ gcnt,
        unsigned int* __restrict__ buf, int GB) {
    __shared__ int hist[NBKT];
    __shared__ int base[NBKT];
    if ((int)blockIdx.x < GB) {
        gemm_att_body<K, N>(blockIdx.x, xf, Wf,
                            att_src, att_dst, h_bf, a_src, a_dst);
    } else {
        const int sb = (int)blockIdx.x - GB;
        const int c0 = sb * SCHUNK;
        const int c1 = (c0 + SCHUNK < E_TOT) ? c0 + SCHUNK : E_TOT;
        for (int t = threadIdx.x; t < NBKT; t += 256) hist[t] = 0;
        __syncthreads();
        // pass 1: histogram by coarse bucket
        for (int i = c0 + threadIdx.x; i < c1; i += 256) {
            const int d = (i < E_RAW) ? ei[E_RAW + i] : (i - E_RAW);
            atomicAdd(&hist[d >> 7], 1);
        }
        __syncthreads();
        // reserve this block's contiguous run in each bucket
        for (int t = threadIdx.x; t < NBKT; t += 256)
            base[t] = atomicAdd(&gcnt[t], hist[t]);
        __syncthreads();
        for (int t = threadIdx.x; t < NBKT; t += 256) hist[t] = 0;
        __syncthreads();
        // pass 2: grouped scatter of packed (s<<7 | d&127) entries
        for (int i = c0 + threadIdx.x; i < c1; i += 256) {
            int s, d;
            if (i < E_RAW) { s = ei[i]; d = ei[E_RAW + i]; }
            else           { s = d = i - E_RAW; }
            const int b = d >> 7;
            const int p = base[b] + atomicAdd(&hist[b], 1);
            if (p < BCAP)
                buf[(size_t)b * BCAP + p] =
                    ((unsigned int)s << 7) | (unsigned int)(d & 127);
        }
    }
}

// ===== bucket -> ELL expansion: one block per bucket, LDS slot tickets =====
__global__ __launch_bounds__(256) void gat_ell_kernel(
        const unsigned int* __restrict__ buf, const int* __restrict__ gcnt,
        int* __restrict__ cnt, unsigned short* __restrict__ srcs) {
    const int b = blockIdx.x;
    __shared__ unsigned int c2[128];
    if (threadIdx.x < 128) c2[threadIdx.x] = 0;
    __syncthreads();
    int n = gcnt[b];
    n = n < BCAP ? n : BCAP;
    const unsigned int* bb = buf + (size_t)b * BCAP;
    for (int i = threadIdx.x; i < n; i += 256) {
        const unsigned int e = bb[i];
        const int dl = (int)(e & 127u);
        const unsigned int s = e >> 7;
        const unsigned int c = atomicAdd(&c2[dl], 1u);
        if (c < CAP)
            srcs[((size_t)((b << 7) + dl) << 6) + c] = (unsigned short)s;
    }
    __syncthreads();
    const int d = (b << 7) + threadIdx.x;
    if (threadIdx.x < 128 && d < N_NODES) {
        unsigned int c = c2[threadIdx.x];
        cnt[d] = (int)(c < CAP ? c : CAP);
    }
}

// ===== shared stage 1+2: per-dst softmax alphas into LDS =====
// Block covers 16 dsts; thread t -> dst t>>4, slots (t&15)*4..+3. Slots >= deg
// are SANITIZED to src=0 with alpha=0, so gather loops need no tail predication
// (0 * finite(row 0) == 0).
__device__ __forceinline__ void softmax_stage(
        const int* __restrict__ cnt, const unsigned short* __restrict__ srcs,
        const float* __restrict__ a_src, const float* __restrict__ a_dst,
        const int d0, float* lalpha, unsigned short* lsrc,
        int* ldeg, float* ladst) {
    const int tid = threadIdx.x;
    if (tid < 16) {
        const int d = d0 + tid;
        int dg = cnt[d];
        ldeg[tid]  = dg < CAP ? dg : CAP;
        ladst[tid] = a_dst[d];
    }
    __syncthreads();
    const int dl = tid >> 4;
    const int so = (tid & 15) * 4;
    const int dg = ldeg[dl];
    const float ad = ladst[dl];
    const ushort4_t s4 =
        *(const ushort4_t*)(srcs + ((size_t)(d0 + dl) << 6) + so);
    float e[4];
    ushort4_t s4w;
    #pragma unroll
    for (int i = 0; i < 4; ++i) {
        if (so + i < dg) {
            const float t = a_src[(int)s4[i]] + ad;
            e[i] = t > 0.0f ? t : NEG_SLOPE * t;
            s4w[i] = s4[i];
        } else {
            e[i] = -1e30f;
            s4w[i] = 0;                      // safe row; alpha will be 0
        }
    }
    float m = fmaxf(fmaxf(e[0], e[1]), fmaxf(e[2], e[3]));
    #pragma unroll
    for (int off = 1; off < 16; off <<= 1) m = fmaxf(m, __shfl_xor(m, off));
    float ex[4], ss = 0.0f;
    #pragma unroll
    for (int i = 0; i < 4; ++i) { ex[i] = __expf(e[i] - m); ss += ex[i]; }
    #pragma unroll
    for (int off = 1; off < 16; off <<= 1) ss += __shfl_xor(ss, off);
    const float rinv = 1.0f / ss;            // ss >= 1 (self-loop => deg >= 1)
    float4 av;
    av.x = ex[0] * rinv; av.y = ex[1] * rinv;
    av.z = ex[2] * rinv; av.w = ex[3] * rinv;
    *(float4*)&lalpha[(dl << 6) + so] = av;
    *(ushort4_t*)&lsrc[(dl << 6) + so] = s4w;
}

// ===== FUSED layer-1 aggregation + layer-2 GEMM + layer-2 att scores =====
// Block = 16 dsts. Stage 3: per-dst 16-lane gather-accumulate over the ELL
// (uniform deg4 loop, sanitized tails). Epilogue: bias+relu rows -> 16x136 LDS
// bf16 A-tile; each wave computes a 16x16 tile of h2 = h1 @ W2 via 4x
// mfma_16x16x32_bf16 + layer-2 att scores via partial dots + LDS reduce.
__global__ __launch_bounds__(256, 8) void gat_aggr1_fused_kernel(
        const int* __restrict__ cnt, const unsigned short* __restrict__ srcs,
        const float* __restrict__ a_src, const float* __restrict__ a_dst,
        const unsigned short* __restrict__ h_bf, const float* __restrict__ bias,
        const short* __restrict__ Wf2,
        const float* __restrict__ att_src2, const float* __restrict__ att_dst2,
        short* __restrict__ hbf2,
        float* __restrict__ a_src2, float* __restrict__ a_dst2) {
    constexpr int N = 128;
    __shared__ __align__(16) float lalpha[1024];   // 16 dsts x 64 slots
    __shared__ __align__(16) unsigned short lsrc[1024];
    __shared__ int   ldeg[16];
    __shared__ float ladst[16];
    __shared__ __align__(16) short lh[16 * 136];   // h1 tile, +8 pad/row
    __shared__ float pspart[64], pdpart[64];       // [wave][row]
    const int tid = threadIdx.x;
    const int d0 = blockIdx.x * 16;          // 3125 blocks x 16 = 50000 exact

    softmax_stage(cnt, srcs, a_src, a_dst, d0, lalpha, lsrc, ldeg, ladst);
    __syncthreads();

    // ---- stage 3: wave w -> dsts w*4..w*4+3; group g (16 lanes) owns one ----
    const int lane = tid & 63;
    const int g    = lane >> 4;
    const int sub  = lane & 15;
    const int dl   = (tid >> 6) * 4 + g;
    const int deg  = ldeg[dl];
    const int base = dl << 6;

    float acc[8];
    #pragma unroll
    for (int c = 0; c < 8; ++c) acc[c] = 0.0f;

    const int deg4 = (deg + 3) & ~3;         // sanitized slots: uniform loop
    for (int j = 0; j < deg4; j += 4) {      // 4 gathers in flight
        const ushort4_t s4 = *(const ushort4_t*)&lsrc[base + j];
        const float4    a4 = *(const float4*)&lalpha[base + j];
        const uint4 h0 = *(const uint4*)(h_bf + (size_t)s4[0] * N + sub * 8);
        const uint4 h1 = *(const uint4*)(h_bf + (size_t)s4[1] * N + sub * 8);
        const uint4 h2 = *(const uint4*)(h_bf + (size_t)s4[2] * N + sub * 8);
        const uint4 h3 = *(const uint4*)(h_bf + (size_t)s4[3] * N + sub * 8);
        fma8(a4.x, h0, acc); fma8(a4.y, h1, acc);
        fma8(a4.z, h2, acc); fma8(a4.w, h3, acc);
    }

    // ---- bias + relu -> bf16 -> LDS A-tile (row dl, cols sub*8..+7) ----
    {
        const float4 b0 = *(const float4*)&bias[sub * 8];
        const float4 b1 = *(const float4*)&bias[sub * 8 + 4];
        float v[8];
        v[0] = fmaxf(acc[0] + b0.x, 0.0f); v[1] = fmaxf(acc[1] + b0.y, 0.0f);
        v[2] = fmaxf(acc[2] + b0.z, 0.0f); v[3] = fmaxf(acc[3] + b0.w, 0.0f);
        v[4] = fmaxf(acc[4] + b1.x, 0.0f); v[5] = fmaxf(acc[5] + b1.y, 0.0f);
        v[6] = fmaxf(acc[6] + b1.z, 0.0f); v[7] = fmaxf(acc[7] + b1.w, 0.0f);
        uint4 p;
        p.x = f2bfu(v[0]) | (f2bfu(v[1]) << 16);
        p.y = f2bfu(v[2]) | (f2bfu(v[3]) << 16);
        p.z = f2bfu(v[4]) | (f2bfu(v[5]) << 16);
        p.w = f2bfu(v[6]) | (f2bfu(v[7]) << 16);
        *(uint4*)&lh[dl * 136 + sub * 8] = p;
    }
    __syncthreads();

    // ---- layer-2 GEMM: wave w -> output cols w*16..+15, all 16 rows ----
    const int w    = tid >> 6;
    const int q    = lane >> 4;
    const int mrow = lane & 15;
    f32x4 acc2 = f32x4{0.f, 0.f, 0.f, 0.f};
    #pragma unroll
    for (int kc = 0; kc < 4; ++kc) {
        const short8 a = *(const short8*)&lh[mrow * 136 + q * 8 + kc * 32];
        const short8 b = *(const short8*)&Wf2[((size_t)(kc * 4 + w) * 64 + lane) * 8];
        acc2 = __builtin_amdgcn_mfma_f32_16x16x32_bf16(a, b, acc2, 0, 0, 0);
    }

    // ---- layer-2 att scores (partial over this wave's 16 cols) + hbf2 ----
    const float as2 = att_src2[w * 16 + mrow];
    const float ad2 = att_dst2[w * 16 + mrow];
    #pragma unroll
    for (int r = 0; r < 4; ++r) {
        const int rl = q * 4 + r;            // local row = dst index in tile
        float ps = acc2[r] * as2;
        float pd = acc2[r] * ad2;
        #pragma unroll
        for (int off = 1; off < 16; off <<= 1) {
            ps += __shfl_xor(ps, off);
            pd += __shfl_xor(pd, off);
        }
        if (mrow == 0) { pspart[w * 16 + rl] = ps; pdpart[w * 16 + rl] = pd; }
        hbf2[(size_t)(d0 + rl) * 64 + w * 16 + mrow] = f2bf(acc2[r]);
    }
    __syncthreads();
    if (tid < 16) {
        a_src2[d0 + tid] = pspart[tid] + pspart[16 + tid]
                         + pspart[32 + tid] + pspart[48 + tid];
        a_dst2[d0 + tid] = pdpart[tid] + pdpart[16 + tid]
                         + pdpart[32 + tid] + pdpart[48 + tid];
    }
}

// ===== layer-2 aggregation + bias + log_softmax (N=64) =====
__global__ __launch_bounds__(256, 8) void gat_aggr2_kernel(
        const int* __restrict__ cnt, const unsigned short* __restrict__ srcs,
        const float* __restrict__ a_src, const float* __restrict__ a_dst,
        const unsigned short* __restrict__ h_bf, const float* __restrict__ bias,
        float* __restrict__ outf) {
    constexpr int N = 64;
    __shared__ __align__(16) float lalpha[1024];   // 16 dsts x 64 slots
    __shared__ __align__(16) unsigned short lsrc[1024];
    __shared__ int   ldeg[16];
    __shared__ float ladst[16];
    const int tid = threadIdx.x;
    const int d0 = blockIdx.x * 16;          // 3125 blocks x 16 = 50000 exact

    softmax_stage(cnt, srcs, a_src, a_dst, d0, lalpha, lsrc, ldeg, ladst);
    __syncthreads();

    // ---- stage 3: wave w -> dsts w*4..w*4+3; group g (16 lanes) owns one ----
    const int lane = tid & 63;
    const int g    = lane >> 4;
    const int sub  = lane & 15;
    const int dl   = (tid >> 6) * 4 + g;
    const int d    = d0 + dl;
    const int deg  = ldeg[dl];
    const int base = dl << 6;

    float acc[4];
    #pragma unroll
    for (int c = 0; c < 4; ++c) acc[c] = 0.0f;

    const int deg4 = (deg + 3) & ~3;         // sanitized slots: uniform loop
    for (int j = 0; j < deg4; j += 4) {      // 4 gathers in flight
        const ushort4_t s4 = *(const ushort4_t*)&lsrc[base + j];
        const float4    a4 = *(const float4*)&lalpha[base + j];
        const uint2 h0 = *(const uint2*)(h_bf + (size_t)s4[0] * N + sub * 4);
        const uint2 h1 = *(const uint2*)(h_bf + (size_t)s4[1] * N + sub * 4);
        const uint2 h2 = *(const uint2*)(h_bf + (size_t)s4[2] * N + sub * 4);
        const uint2 h3 = *(const uint2*)(h_bf + (size_t)s4[3] * N + sub * 4);
        fma4(a4.x, h0, acc); fma4(a4.y, h1, acc);
        fma4(a4.z, h2, acc); fma4(a4.w, h3, acc);
    }

    // ---- epilogue: bias + log_softmax; lane sub holds cols sub*4..+3 ----
    float v[4];
    #pragma unroll
    for (int c = 0; c < 4; ++c) v[c] = acc[c] + bias[sub * 4 + c];
    float mm = fmaxf(fmaxf(v[0], v[1]), fmaxf(v[2], v[3]));
    #pragma unroll
    for (int off = 1; off < 16; off <<= 1) mm = fmaxf(mm, __shfl_xor(mm, off));
    float es = __expf(v[0] - mm) + __expf(v[1] - mm)
             + __expf(v[2] - mm) + __expf(v[3] - mm);
    #pragma unroll
    for (int off = 1; off < 16; off <<= 1) es += __shfl_xor(es, off);
    const float ls = logf(es);
    float4 o;
    o.x = v[0] - mm - ls; o.y = v[1] - mm - ls;
    o.z = v[2] - mm - ls; o.w = v[3] - mm - ls;
    *(float4*)&outf[(size_t)d * N + sub * 4] = o;
}

extern "C" void kernel_launch(void* const* d_in, const int* in_sizes, int n_in,
                              void* d_out, int out_size, void* d_ws, size_t ws_size,
                              hipStream_t stream) {
    const float* x        = (const float*)d_in[0];
    const int*   ei       = (const int*)  d_in[1];
    const float* W1       = (const float*)d_in[2];
    const float* att_src1 = (const float*)d_in[3];
    const float* att_dst1 = (const float*)d_in[4];
    const float* b1       = (const float*)d_in[5];
    const float* W2       = (const float*)d_in[6];
    const float* att_src2 = (const float*)d_in[7];
    const float* att_dst2 = (const float*)d_in[8];
    const float* b2       = (const float*)d_in[9];
    float* out = (float*)d_out;
    float* ws  = (float*)d_ws;

    // workspace layout (float units; 16B alignment holds for hbf*/Wf)
    float* a_src1 = ws;                              //  50,000
    float* a_dst1 = a_src1 + 50000;
    float* a_src2 = a_dst1 + 50000;
    float* a_dst2 = a_src2 + 50000;
    int*   cnt    = (int*)(a_dst2 + 50000);          //  50,000
    int*   gcnt   = cnt + 50000;                     //     512 (392 used)
    unsigned int*   buf  = (unsigned int*)(gcnt + 512);   // 392*2944 u32 bucket lists
    unsigned short* srcs = (unsigned short*)(buf + (size_t)NBKT * BCAP); // 3.2M ushort ELL
    short* hbf1   = (short*)(srcs + (size_t)N_NODES * CAP);  // 6,400,000 bf16
    short* hbf2   = hbf1  + 6400000;                 // 3,200,000 bf16 (own buffer:
                                                     //  hbf1 still read while written)
    short* Wf1    = hbf2  + 3200000;                 //    32,768 bf16
    short* Wf2    = Wf1   + 32768;                   //     8,192 bf16

    const int GB = (N_NODES + 63) / 64;              // 782 gemm blocks

    // ---- weight swizzles + gcnt zeroing (single launch, no memset) ----
    gat_wf12_kernel<<<160, 256, 0, stream>>>(W1, Wf1, W2, Wf2, gcnt);

    // ---- layer-1 GEMM + coarse edge binning, fused (independent, co-scheduled) ----
    gat_fat1_kernel<256, 128><<<GB + SB, 256, 0, stream>>>(
        x, Wf1, att_src1, att_dst1, hbf1, a_src1, a_dst1,
        ei, gcnt, buf, GB);

    // ---- bucket lists -> ELL (cnt + ushort srcs), XCD-local writes ----
    gat_ell_kernel<<<NBKT, 256, 0, stream>>>(buf, gcnt, cnt, srcs);

    // ---- layer-1 aggregation + fused layer-2 GEMM + att scores ----
    gat_aggr1_fused_kernel<<<3125, 256, 0, stream>>>(
        cnt, srcs, a_src1, a_dst1, (const unsigned short*)hbf1, b1,
        Wf2, att_src2, att_dst2, hbf2, a_src2, a_dst2);

    // ---- layer-2 aggregation + log_softmax ----
    gat_aggr2_kernel<<<3125, 256, 0, stream>>>(
        cnt, srcs, a_src2, a_dst2, (const unsigned short*)hbf2, b2,
        out);
}